// Round 1
// 271.665 us; speedup vs baseline: 1.0790x; 1.0790x over previous
//
#include <hip/hip_runtime.h>
#include <hip/hip_bf16.h>

// Problem constants (fixed by the reference).
constexpr int B = 16;
constexpr int D = 256;       // feature dim
constexpr int L = 4096;      // sequence length
constexpr int N = 4096;      // queries per batch
constexpr int TS = 64;       // l-tile size for the scan
constexpr int NT = L / TS;   // 64 tiles per (b,d) row

typedef float v4f __attribute__((ext_vector_type(4)));

// ---------------------------------------------------------------------------
// K1: fused per-row tile sums + exclusive scan of tile sums. (unchanged)
// One block per (b,d) row (4096 blocks). float4 loads, fully coalesced.
// P[row][t] = exclusive prefix of tile sums; cs_t[b][L][d] = row total.
// ---------------------------------------------------------------------------
__global__ __launch_bounds__(256) void row_scan(const float* __restrict__ feat,
                                                float* __restrict__ P,
                                                float* __restrict__ cs_t) {
    __shared__ float tsum[NT];
    int row = blockIdx.x;            // [0, B*D)
    int tid = threadIdx.x;
    const float4* fr = (const float4*)(feat + (size_t)row * L);

    float s[4];
    #pragma unroll
    for (int r = 0; r < 4; ++r) {
        float4 v = fr[r * 256 + tid];
        s[r] = (v.x + v.y) + (v.z + v.w);
    }
    #pragma unroll
    for (int r = 0; r < 4; ++r) {
        float v = s[r];
        #pragma unroll
        for (int off = 1; off < 16; off <<= 1) v += __shfl_xor(v, off, 64);
        if ((tid & 15) == 0) tsum[r * 16 + (tid >> 4)] = v;
    }
    __syncthreads();

    if (tid < NT) {
        float v = tsum[tid];
        float incl = v;
        #pragma unroll
        for (int off = 1; off < 64; off <<= 1) {
            float u = __shfl_up(incl, off, 64);
            if (tid >= off) incl += u;
        }
        P[row * NT + tid] = incl - v;            // exclusive tile offset
        if (tid == NT - 1) {                     // row total -> l = L column
            int b = row >> 8, d = row & 255;     // D == 256
            cs_t[((size_t)b * (L + 1) + L) * D + d] = incl;
        }
    }
}

// ---------------------------------------------------------------------------
// K2: per-tile exclusive scan + transpose — CHUNKED REGISTER SCAN rewrite.
// Block = (b, 64-d tile, 64-l tile), 256 threads, tile[d][l] in LDS (pad 65).
//
// Scan phase: lane holds 4 CONTIGUOUS l-elements (one float4). A wave covers
// 4 rows per pass (16 lanes x 4 elems each), 4 passes = its 16 rows.
//   - float4 global load: 4 rows x 256B per wave instr (line-coalesced),
//     4 load instrs/wave instead of 16.
//   - local 3-add scan + 16-lane segmented shfl_up (4 steps, DPP-eligible)
//     instead of 6-step 64-wide bpermute scan per row: 16 vs 96 cross-lane
//     ops per wave.
//   - single LDS write of the finished values (+P offset). No phase-1
//     staging round-trip, one barrier removed.
// Store phase: lane stores a float4 (4 consecutive d of one l): 4 instrs of
// 1KB coalesced instead of 16 x 256B. All LDS patterns are <=2-way (free).
// ---------------------------------------------------------------------------
__global__ __launch_bounds__(256) void transpose_scan(const float* __restrict__ feat,
                                                      const float* __restrict__ P,
                                                      float* __restrict__ cs_t) {
    __shared__ float tile[64][65];   // [d][l], stride 65 -> conflict-free cols
    __shared__ float poff[64];
    int bid = blockIdx.x;            // grid = B * (D/64) * NT = 4096
    int t   = bid & 63;              // l tile
    int dt  = (bid >> 6) & 3;        // d tile
    int b   = bid >> 8;
    int tid = threadIdx.x;
    int lane = tid & 63;
    int w    = tid >> 6;             // wave 0..3 -> rows [w*16, w*16+16)
    int q    = lane >> 4;            // row-in-pass 0..3
    int p    = lane & 15;            // l-chunk 0..15 (4 elems each)
    int d0  = dt * 64;
    int l0  = t * TS;

    if (tid < 64) poff[tid] = P[(b * D + d0 + tid) * NT + t];
    __syncthreads();

    const float* fbase = feat + (size_t)(b * D + d0) * L + l0;
    #pragma unroll
    for (int r = 0; r < 4; ++r) {
        int dd = w * 16 + r * 4 + q;
        v4f v = *(const v4f*)(fbase + (size_t)dd * L + p * 4);
        float x = v.x, y = v.y, z = v.z, u = v.w;
        float tot = ((x + y) + z) + u;
        // inclusive scan of chunk totals within each 16-lane segment
        float incl = tot;
        #pragma unroll
        for (int off = 1; off < 16; off <<= 1) {
            float s = __shfl_up(incl, off, 16);
            if (p >= off) incl += s;
        }
        float base = (incl - tot) + poff[dd];    // exclusive chunk offset
        tile[dd][p * 4 + 0] = base;
        tile[dd][p * 4 + 1] = base + x;
        tile[dd][p * 4 + 2] = base + (x + y);
        tile[dd][p * 4 + 3] = base + ((x + y) + z);
    }
    __syncthreads();

    // store: thread -> (l = k*16 + tid>>4, d4 = (tid&15)*4); float4 per lane.
    #pragma unroll
    for (int k = 0; k < 4; ++k) {
        int l  = k * 16 + (tid >> 4);
        int d4 = (tid & 15) * 4;
        v4f val;
        val.x = tile[d4 + 0][l];
        val.y = tile[d4 + 1][l];
        val.z = tile[d4 + 2][l];
        val.w = tile[d4 + 3][l];
        *(v4f*)(cs_t + ((size_t)b * (L + 1) + l0 + l) * D + d0 + d4) = val;
    }
}

// ---------------------------------------------------------------------------
// K3: one wave per query — now with XCD-chunked block swizzle.
// Default round-robin puts consecutive blocks on different XCDs, so every
// XCD's 4MiB L2 thrashes all 16 batches' cs_t tables (67MB). Chunked swizzle
// gives XCD k blocks [k*2048, (k+1)*2048) = exactly batches {2k, 2k+1}:
// per-XCD read working set 67MB -> 8.4MB. grid=16384, 16384%8==0 -> bijective.
// ---------------------------------------------------------------------------
__global__ __launch_bounds__(256) void pool_queries(const float* __restrict__ cs_t,
                                                    const int* __restrict__ tois,
                                                    float* __restrict__ out) {
    int nchunk = (int)gridDim.x >> 3;                 // blocks per XCD chunk
    int bid    = blockIdx.x;
    int nbid   = (bid & 7) * nchunk + (bid >> 3);     // XCD-chunked remap
    int gw     = nbid * 4 + (threadIdx.x >> 6);       // query id
    int lane   = threadIdx.x & 63;
    int b = gw >> 12;                 // N == 4096
    int2 se = ((const int2*)tois)[gw];
    int s = se.x, e = se.y;

    const size_t base = (size_t)b * (L + 1);
    const v4f* r_s = (const v4f*)(cs_t + (base + s) * D);
    const v4f* r_e = (const v4f*)(cs_t + (base + e) * D);

    v4f cs0 = r_s[lane];              // row s
    v4f cs1 = r_s[lane + 64];         // row s+1 (contiguous)
    v4f ce1 = r_e[lane - 64];         // row e-1 (contiguous below e)
    v4f ce0 = r_e[lane];              // row e

    float inv = 1.0f / (float)(e - s);
    v4f head = cs1 - cs0;
    v4f avg  = (ce0 - cs0) * inv;
    v4f tail = ce0 - ce1;

    v4f* orow = (v4f*)(out + (size_t)gw * (3 * D));   // 192 v4f per row
    __builtin_nontemporal_store(head, orow + lane);
    __builtin_nontemporal_store(avg,  orow + 64 + lane);
    __builtin_nontemporal_store(tail, orow + 128 + lane);

    // counts output: (i+1)*N as float32 values (harness reads f32)
    if (gw == 0 && lane < B)
        out[(size_t)B * N * (3 * D) + lane] = (float)((lane + 1) * N);
}

// ---------------------------------------------------------------------------
// Fallback (only if ws_size is too small): direct span summation.
// ---------------------------------------------------------------------------
__global__ __launch_bounds__(256) void pool_direct(const float* __restrict__ feat,
                                                   const int* __restrict__ tois,
                                                   float* __restrict__ out) {
    int gw   = (blockIdx.x * blockDim.x + threadIdx.x) >> 6;
    int lane = threadIdx.x & 63;
    if (gw >= B * N) return;
    int b = gw >> 12;
    int s = tois[gw * 2 + 0];
    int e = tois[gw * 2 + 1];
    float inv = 1.0f / (float)(e - s);
    float* orow = out + (size_t)gw * (3 * D);
    #pragma unroll
    for (int c = 0; c < 4; ++c) {
        int d = c * 64 + lane;
        const float* f = feat + ((size_t)(b * D + d)) * L;
        float sum = 0.f;
        for (int j = s; j < e; ++j) sum += f[j];
        orow[d]         = f[s];
        orow[D + d]     = sum * inv;
        orow[2 * D + d] = f[e - 1];
    }
    if (gw == 0 && lane < B)
        out[(size_t)B * N * (3 * D) + lane] = (float)((lane + 1) * N);
}

extern "C" void kernel_launch(void* const* d_in, const int* in_sizes, int n_in,
                              void* d_out, int out_size, void* d_ws, size_t ws_size,
                              hipStream_t stream) {
    const float* feat = (const float*)d_in[0];
    const int*   tois = (const int*)d_in[1];
    float*       out  = (float*)d_out;

    const size_t cs_elems = (size_t)B * (L + 1) * D;      // 16,781,312
    const size_t p_elems  = (size_t)B * D * NT;           // 262,144
    const size_t need     = (cs_elems + p_elems) * sizeof(float);  // ~68.2 MB

    if (ws_size >= need) {
        float* cs_t = (float*)d_ws;
        float* P    = cs_t + cs_elems;

        row_scan<<<B * D, 256, 0, stream>>>(feat, P, cs_t);
        transpose_scan<<<B * (D / 64) * NT, 256, 0, stream>>>(feat, P, cs_t);
        pool_queries<<<B * N / 4, 256, 0, stream>>>(cs_t, tois, out);
    } else {
        pool_direct<<<B * N / 4, 256, 0, stream>>>(feat, tois, out);
    }
}

// Round 2
// 270.000 us; speedup vs baseline: 1.0856x; 1.0062x over previous
//
#include <hip/hip_runtime.h>

// Problem constants (fixed by the reference).
constexpr int B = 16;
constexpr int D = 256;       // feature dim
constexpr int L = 4096;      // sequence length
constexpr int N = 4096;      // queries per batch
constexpr int TS = 64;       // s-tile size
constexpr int NTL = L / TS;  // 64 s-tiles
constexpr int NBIN = B * NTL;   // 1024 bins
constexpr int WIN = 128;     // l-window per tile (MAX_SPAN=64 -> span fits)
constexpr int SD = 65;       // LDS row stride in floats (conflict-free reads)

typedef float v4f __attribute__((ext_vector_type(4)));

// ---------------------------------------------------------------------------
// Binning: queries grouped by (b, start>>6). Because end <= start+64, the
// whole span of a query in bin t lies inside l-window [64t, 64t+128): head,
// tail and the span sum are all LOCAL to that window. The global cumsum
// (cs_t, 67MB write + 256MB scattered re-read) is unnecessary.
// ---------------------------------------------------------------------------

// K_hist: per-block LDS histogram (block = 256 consecutive queries, same b).
__global__ __launch_bounds__(256) void q_hist(const int* __restrict__ tois,
                                              int* __restrict__ cnt) {
    __shared__ int h[NTL];
    int tid = threadIdx.x;
    if (tid < NTL) h[tid] = 0;
    __syncthreads();
    int q = blockIdx.x * 256 + tid;
    int s = tois[q * 2];
    atomicAdd(&h[s >> 6], 1);
    __syncthreads();
    int b = blockIdx.x >> 4;           // 16 blocks per batch
    if (tid < NTL) { int v = h[tid]; if (v) atomicAdd(&cnt[b * NTL + tid], v); }
}

// K_off: exclusive scan of the 1024 bin counts (single block, 1024 threads).
__global__ __launch_bounds__(1024) void q_offsets(const int* __restrict__ cnt,
                                                  int* __restrict__ off) {
    __shared__ int wt[16];
    int tid = threadIdx.x;
    int v = cnt[tid];
    int incl = v;
    #pragma unroll
    for (int o = 1; o < 64; o <<= 1) {
        int u = __shfl_up(incl, o, 64);
        if ((tid & 63) >= o) incl += u;
    }
    if ((tid & 63) == 63) wt[tid >> 6] = incl;
    __syncthreads();
    if (tid == 0) {
        int a = 0;
        #pragma unroll
        for (int i = 0; i < 16; ++i) { int t2 = wt[i]; wt[i] = a; a += t2; }
        off[NBIN] = a;                 // = B*N
    }
    __syncthreads();
    off[tid] = wt[tid >> 6] + incl - v;
}

// K_scatter: qlist[off[bin] + pos] = q. Order within a bin is irrelevant.
// Also emits the counts tail of the output.
__global__ __launch_bounds__(256) void q_scatter(const int* __restrict__ tois,
                                                 const int* __restrict__ off,
                                                 int* __restrict__ cur,
                                                 int* __restrict__ qlist,
                                                 float* __restrict__ out) {
    int tid = threadIdx.x;
    int q = blockIdx.x * 256 + tid;
    int s = tois[q * 2];
    int b = q >> 12;                   // N == 4096
    int bin = b * NTL + (s >> 6);
    int pos = atomicAdd(&cur[bin], 1);
    qlist[off[bin] + pos] = q;
    if (q < B) out[(size_t)B * N * (3 * D) + q] = (float)((q + 1) * N);
}

// ---------------------------------------------------------------------------
// K_pool: block = (b, l-tile t, 64-d slice dq). Loads feat[b, d0..d0+64,
// l0..l0+128) coalesced (float4), transposes into LDS cs[l][d], exclusive-
// scans each d-column along l (4 waves x 32-quarter + fixup), then each wave
// serves one binned query per iteration:
//   head = cs[si+1]-cs[si], avg = (cs[ei]-cs[si])*inv, tail = cs[ei]-cs[ei-1]
// 4 conflict-free LDS reads/lane + 3 coalesced 256B nontemporal stores.
// LDS 35.3 KB -> 4 blocks/CU (16 waves). XCD-chunked swizzle: adjacent tiles
// (which share half their window) land on the same XCD -> overlap reads are
// L2 hits.
// ---------------------------------------------------------------------------
__global__ __launch_bounds__(256, 4) void pool(const float* __restrict__ feat,
                                               const int* __restrict__ tois,
                                               const int* __restrict__ off,
                                               const int* __restrict__ qlist,
                                               float* __restrict__ out) {
    __shared__ float cs[WIN][SD];      // [l][d], 33,280 B
    __shared__ float qtot[4][64];
    __shared__ float qoff[4][64];

    int bid  = blockIdx.x;
    int nbid = (bid & 7) * ((int)gridDim.x >> 3) + (bid >> 3);  // XCD chunks
    int dq = nbid & 3;
    int t  = (nbid >> 2) & 63;
    int b  = nbid >> 8;
    int bin = b * NTL + t;
    int qs0 = off[bin];
    int nq  = off[bin + 1] - qs0;
    if (nq == 0) return;               // t==63 is always empty (s < L-64)

    int tid = threadIdx.x, lane = tid & 63, wv = tid >> 6;
    int d0 = dq * 64, l0 = t * TS;

    // ---- load + transpose: 64 rows x 512B, fully coalesced ----
    const float* fb = feat + ((size_t)(b * D + d0)) * L + l0;
    #pragma unroll
    for (int k = 0; k < 8; ++k) {
        int g = k * 256 + tid;
        int r = g >> 5, cc = g & 31;   // row, float4-chunk along l
        v4f v = *(const v4f*)(fb + (size_t)r * L + cc * 4);
        cs[cc * 4 + 0][r] = v.x;
        cs[cc * 4 + 1][r] = v.y;
        cs[cc * 4 + 2][r] = v.z;
        cs[cc * 4 + 3][r] = v.w;
    }
    __syncthreads();

    // ---- exclusive scan along l (in place): wave wv scans quarter wv ----
    {
        float c = 0.f;
        #pragma unroll
        for (int i = 0; i < 32; ++i) {
            int l = wv * 32 + i;
            float v = cs[l][lane];
            cs[l][lane] = c;
            c += v;
        }
        qtot[wv][lane] = c;
    }
    __syncthreads();
    if (tid < 64) {
        float o = 0.f;
        #pragma unroll
        for (int qr = 0; qr < 4; ++qr) { float v = qtot[qr][tid]; qoff[qr][tid] = o; o += v; }
    }
    __syncthreads();
    if (wv) {
        float o = qoff[wv][lane];
        #pragma unroll
        for (int i = 0; i < 32; ++i) cs[wv * 32 + i][lane] += o;
    }
    __syncthreads();

    // ---- query phase: wave wv handles queries it = wv, wv+4, ... ----
    const int2* tp = (const int2*)tois;
    for (int it = wv; it < nq; it += 4) {
        int q = qlist[qs0 + it];       // uniform per wave -> scalar load
        int2 se = tp[q];
        int si = se.x - l0;            // 0..63
        int ei = se.y - l0;            // si+1 .. si+64 <= 127
        float a0 = cs[si][lane];
        float a1 = cs[si + 1][lane];
        float e0 = cs[ei][lane];
        float e1 = cs[ei - 1][lane];
        float inv = 1.0f / (float)(se.y - se.x);
        float head = a1 - a0;
        float avg  = (e0 - a0) * inv;
        float tail = e0 - e1;
        float* orow = out + (size_t)q * (3 * D) + d0 + lane;
        __builtin_nontemporal_store(head, orow);
        __builtin_nontemporal_store(avg,  orow + D);
        __builtin_nontemporal_store(tail, orow + 2 * D);
    }
}

// ---------------------------------------------------------------------------
// Fallback (only if ws_size is too small): direct span summation.
// ---------------------------------------------------------------------------
__global__ __launch_bounds__(256) void pool_direct(const float* __restrict__ feat,
                                                   const int* __restrict__ tois,
                                                   float* __restrict__ out) {
    int gw   = (blockIdx.x * blockDim.x + threadIdx.x) >> 6;
    int lane = threadIdx.x & 63;
    if (gw >= B * N) return;
    int b = gw >> 12;
    int s = tois[gw * 2 + 0];
    int e = tois[gw * 2 + 1];
    float inv = 1.0f / (float)(e - s);
    float* orow = out + (size_t)gw * (3 * D);
    #pragma unroll
    for (int c = 0; c < 4; ++c) {
        int d = c * 64 + lane;
        const float* f = feat + ((size_t)(b * D + d)) * L;
        float sum = 0.f;
        for (int j = s; j < e; ++j) sum += f[j];
        orow[d]         = f[s];
        orow[D + d]     = sum * inv;
        orow[2 * D + d] = f[e - 1];
    }
    if (gw == 0 && lane < B)
        out[(size_t)B * N * (3 * D) + lane] = (float)((lane + 1) * N);
}

extern "C" void kernel_launch(void* const* d_in, const int* in_sizes, int n_in,
                              void* d_out, int out_size, void* d_ws, size_t ws_size,
                              hipStream_t stream) {
    const float* feat = (const float*)d_in[0];
    const int*   tois = (const int*)d_in[1];
    float*       out  = (float*)d_out;

    // workspace layout: cnt[1024] | cur[1024] | off[1025] | qlist[65536]
    int* cnt   = (int*)d_ws;
    int* cur   = cnt + NBIN;
    int* off   = cur + NBIN;
    int* qlist = off + NBIN + 1;
    const size_t need = (size_t)(NBIN * 2 + NBIN + 1 + B * N) * sizeof(int);  // ~278 KB

    if (ws_size >= need) {
        hipMemsetAsync(cnt, 0, (size_t)NBIN * 2 * sizeof(int), stream);  // cnt+cur
        q_hist   <<<B * N / 256, 256, 0, stream>>>(tois, cnt);
        q_offsets<<<1, 1024, 0, stream>>>(cnt, off);
        q_scatter<<<B * N / 256, 256, 0, stream>>>(tois, off, cur, qlist, out);
        pool     <<<B * (D / 64) * NTL, 256, 0, stream>>>(feat, tois, off, qlist, out);
    } else {
        pool_direct<<<B * N / 4, 256, 0, stream>>>(feat, tois, out);
    }
}

// Round 3
// 263.102 us; speedup vs baseline: 1.1141x; 1.0262x over previous
//
#include <hip/hip_runtime.h>

// Problem constants (fixed by the reference).
constexpr int B   = 16;
constexpr int D   = 256;     // feature dim
constexpr int L   = 4096;    // sequence length
constexpr int N   = 4096;    // queries per batch
constexpr int TS  = 64;      // s-tile width
constexpr int NTU = 63;      // occupied s-tiles: s in [0, L-64) -> (s>>6) <= 62
constexpr int WIN = 128;     // l-window per tile (MAX_SPAN=64 -> span fits)
constexpr int SDL = 129;     // LDS l-stride (odd -> all accesses <=2 lanes/bank)
constexpr int QCH = 1024;    // query chunk for self-binning (any distribution)

// ---------------------------------------------------------------------------
// Single fused kernel. Block = (b, s-tile t, 64-d slice dq).
//
// MAX_SPAN=64 => every query with s>>6 == t lies entirely inside the window
// [64t, 64t+128): head, tail, and the span sum are LOCAL. No global cumsum.
//
// Phases:
//  1. Stage feat[b, d0:d0+64, l0:l0+128) into LDS cs[d][l] (stride 129).
//     b32 loads: 256B/instr coalesced; LDS writes bank-conflict-free.
//  2. Exclusive scan along l per d-column: 4 waves x 32-l quarters + fixup.
//     All LDS ops are 2 lanes/bank (free).
//  3. Self-binning: scan this batch's tois (32KB, L2-resident — redundant
//     reads across the batch's 252 blocks all hit L2 thanks to the XCD
//     swizzle) in 1024-query chunks, compacting matches into an LDS list
//     via LDS atomics, packing (q | si<<16 | len<<22) so the hot loop does
//     no global gathers. Replaces 4 binning dispatches + qlist round-trip.
//  4. Query loop: wave wv serves lq[wv::4]. 4 conflict-free b32 LDS reads
//     + 3 coalesced 256B nontemporal stores per query.
//
// LDS: 33,024 + 1,024 + 1,024 + 4,096 + 4 = 39,172 B -> 4 blocks/CU.
// Grid 4032 = 16*63*4; 4032 % 8 == 0 -> bijective XCD-chunked swizzle,
// 504 blocks/XCD = exactly 2 batches (feat slice L3-resident, tois slice
// L2-resident, window overlap between adjacent t L2-hit).
// ---------------------------------------------------------------------------
__global__ __launch_bounds__(256, 4) void pool(const float* __restrict__ feat,
                                               const int* __restrict__ tois,
                                               float* __restrict__ out) {
    __shared__ float cs[64][SDL];      // [d][l] -> exclusive prefix along l
    __shared__ float qtot[4][64];
    __shared__ float qoff[4][64];
    __shared__ int   lq[QCH];
    __shared__ int   lcnt;

    int bid  = blockIdx.x;
    int nbid = (bid & 7) * ((int)gridDim.x >> 3) + (bid >> 3);  // XCD chunks
    int dq = nbid & 3;
    int tb = nbid >> 2;
    int t  = tb % NTU;
    int b  = tb / NTU;
    int tid = threadIdx.x, lane = tid & 63, wv = tid >> 6;
    int d0 = dq * 64, l0 = t * TS;

    if (bid == 0 && tid < B)           // counts tail: (i+1)*N as f32
        out[(size_t)B * N * (3 * D) + tid] = (float)((tid + 1) * N);

    // ---- phase 1: stage window, conflict-free ----
    const float* fb = feat + ((size_t)(b * D + d0)) * L + l0;
    #pragma unroll
    for (int k = 0; k < 32; ++k) {
        int g = k * 256 + tid;         // 0..8191
        int d = g >> 7, l = g & 127;   // wave spans 64 consecutive l of one d
        cs[d][l] = fb[(size_t)d * L + l];
    }
    __syncthreads();

    // ---- phase 2: exclusive scan along l (wave wv owns quarter wv) ----
    {
        float c = 0.f;
        #pragma unroll
        for (int i = 0; i < 32; ++i) {
            int l = wv * 32 + i;
            float v = cs[lane][l];     // 64 rows, same col: 2 lanes/bank
            cs[lane][l] = c;
            c += v;
        }
        qtot[wv][lane] = c;
    }
    __syncthreads();
    if (tid < 64) {
        float o = 0.f;
        #pragma unroll
        for (int q4 = 0; q4 < 4; ++q4) { float v = qtot[q4][tid]; qoff[q4][tid] = o; o += v; }
    }
    __syncthreads();
    if (wv) {
        float o = qoff[wv][lane];
        #pragma unroll
        for (int i = 0; i < 32; ++i) cs[lane][wv * 32 + i] += o;
    }

    // ---- phases 3+4: self-binning in chunks, then serve queries ----
    const int4* tp4 = (const int4*)tois + ((size_t)b * N >> 1);  // 2 queries/int4
    for (int ch = 0; ch < N / QCH; ++ch) {
        __syncthreads();               // lq from previous chunk consumed
        if (tid == 0) lcnt = 0;
        __syncthreads();
        #pragma unroll
        for (int j = 0; j < 2; ++j) {
            int idx2 = ch * (QCH / 2) + j * 256 + tid;   // coalesced int4
            int4 v = tp4[idx2];
            int ql0 = idx2 * 2;
            if ((v.x >> 6) == t) {
                int pos = atomicAdd(&lcnt, 1);
                lq[pos] = (b * N + ql0) | ((v.x - l0) << 16) | ((v.y - v.x) << 22);
            }
            if ((v.z >> 6) == t) {
                int pos = atomicAdd(&lcnt, 1);
                lq[pos] = (b * N + ql0 + 1) | ((v.z - l0) << 16) | ((v.w - v.z) << 22);
            }
        }
        __syncthreads();
        int n = lcnt;
        for (int it = wv; it < n; it += 4) {
            int p   = lq[it];          // wave-uniform -> broadcast
            int q   = p & 0xFFFF;
            int si  = (p >> 16) & 63;
            int len = (unsigned)p >> 22;       // 1..64
            int ei  = si + len;                // <= 127
            float a0 = cs[lane][si];           // all four: 2 lanes/bank
            float a1 = cs[lane][si + 1];
            float e0 = cs[lane][ei];
            float e1 = cs[lane][ei - 1];
            float inv  = 1.0f / (float)len;
            float head = a1 - a0;
            float avg  = (e0 - a0) * inv;
            float tail = e0 - e1;
            float* orow = out + (size_t)q * (3 * D) + d0 + lane;
            __builtin_nontemporal_store(head, orow);
            __builtin_nontemporal_store(avg,  orow + D);
            __builtin_nontemporal_store(tail, orow + 2 * D);
        }
    }
}

extern "C" void kernel_launch(void* const* d_in, const int* in_sizes, int n_in,
                              void* d_out, int out_size, void* d_ws, size_t ws_size,
                              hipStream_t stream) {
    const float* feat = (const float*)d_in[0];
    const int*   tois = (const int*)d_in[1];
    float*       out  = (float*)d_out;
    (void)d_ws; (void)ws_size;         // no workspace needed

    pool<<<B * NTU * 4, 256, 0, stream>>>(feat, tois, out);
}